// Round 1
// baseline (1502.940 us; speedup 1.0000x reference)
//
#include <hip/hip_runtime.h>
#include <cstdint>
#include <cstddef>

#define NTOK 4096   // B*S = 2*2048
#define DM   1024   // D_MODEL
#define DFF  4096   // D_FF
#define NE   8      // experts

typedef __attribute__((ext_vector_type(8))) __bf16 bf16x8;
typedef __attribute__((ext_vector_type(4))) float  f32x4;

// round-to-nearest-even fp32 -> bf16
__device__ __forceinline__ unsigned short f2bf(float f) {
  union { float f; unsigned int u; } c; c.f = f;
  unsigned int u = c.u;
  return (unsigned short)((u + 0x7fffu + ((u >> 16) & 1u)) >> 16);
}

// async global->LDS, 16B per lane (global_load_lds_dwordx4)
__device__ __forceinline__ void async16(const void* g, void* l) {
  __builtin_amdgcn_global_load_lds(
      (const __attribute__((address_space(1))) void*)(uintptr_t)g,
      (__attribute__((address_space(3))) void*)(uint32_t)(uintptr_t)l,
      16, 0, 0);
}

// ---------------- x fp32 -> bf16 ----------------
__global__ void k_cvt_x(const float* __restrict__ x, unsigned short* __restrict__ xb) {
  int i = (blockIdx.x * 256 + threadIdx.x) * 4;
  float4 v = *(const float4*)(x + i);
  ushort4 o;
  o.x = f2bf(v.x); o.y = f2bf(v.y); o.z = f2bf(v.z); o.w = f2bf(v.w);
  *(ushort4*)(xb + i) = o;
}

// ---------------- transpose + convert: src[R][C] fp32 -> dst[C][R] bf16 (per expert z) ----
__global__ void k_transpose_bf(const float* __restrict__ src, unsigned short* __restrict__ dst,
                               int R, int C) {
  __shared__ float tile[32][33];
  int e = blockIdx.z;
  src += (size_t)e * R * C;
  dst += (size_t)e * R * C;
  int tx = threadIdx.x, ty = threadIdx.y;
  int c = blockIdx.x * 32 + tx;
#pragma unroll
  for (int q = 0; q < 4; q++) {
    int r = blockIdx.y * 32 + q * 8 + ty;
    tile[q * 8 + ty][tx] = src[(size_t)r * C + c];
  }
  __syncthreads();
#pragma unroll
  for (int q = 0; q < 4; q++) {
    dst[(size_t)(blockIdx.x * 32 + q * 8 + ty) * R + blockIdx.y * 32 + tx] =
        f2bf(tile[tx][q * 8 + ty]);
  }
}

// ---------------- router: logits, softmax, top-2, aux stats, token lists -------------
__global__ void k_router(const float* __restrict__ x, const float* __restrict__ Wr,
                         const float* __restrict__ br, int* __restrict__ cnt,
                         int* __restrict__ fcnt, float* __restrict__ Psum,
                         int* __restrict__ toklist, float* __restrict__ wlist) {
  __shared__ float sP[NE];
  __shared__ int sF[NE];
  int tid = threadIdx.x;
  if (tid < NE) { sP[tid] = 0.f; sF[tid] = 0; }
  __syncthreads();
  int tok = blockIdx.x * 32 + (tid >> 3);  // 8 lanes per token, 32 tokens/block
  int e = tid & 7;
  const float* xr = x + (size_t)tok * DM;
  float acc = 0.f;
#pragma unroll 4
  for (int i = 0; i < DM; i += 4) {
    float4 xv = *(const float4*)(xr + i);
    acc = fmaf(xv.x, Wr[(i + 0) * NE + e], acc);
    acc = fmaf(xv.y, Wr[(i + 1) * NE + e], acc);
    acc = fmaf(xv.z, Wr[(i + 2) * NE + e], acc);
    acc = fmaf(xv.w, Wr[(i + 3) * NE + e], acc);
  }
  acc += br[e];
  // softmax over the 8-lane group (group stays inside one 64-lane wave)
  float m = acc;
  for (int s = 1; s < 8; s <<= 1) m = fmaxf(m, __shfl_xor(m, s));
  float p = expf(acc - m);
  float sum = p;
  for (int s = 1; s < 8; s <<= 1) sum += __shfl_xor(sum, s);
  float prob = p / sum;
  atomicAdd(&sP[e], prob);
  int lanebase = (tid & 63) & ~7;
  float pv[8];
#pragma unroll
  for (int j = 0; j < 8; j++) pv[j] = __shfl(prob, lanebase + j);
  if (e == 0) {
    // top-1 (== argmax for f-histogram); ties -> lowest index, matching jax
    int i1 = 0; float v1 = pv[0];
#pragma unroll
    for (int j = 1; j < 8; j++) if (pv[j] > v1) { v1 = pv[j]; i1 = j; }
    int i2 = -1; float v2 = -1.f;
#pragma unroll
    for (int j = 0; j < 8; j++) if (j != i1 && pv[j] > v2) { v2 = pv[j]; i2 = j; }
    float inv = 1.f / (v1 + v2);
    int s1 = atomicAdd(&cnt[i1], 1);
    toklist[i1 * NTOK + s1] = tok; wlist[i1 * NTOK + s1] = v1 * inv;
    int s2 = atomicAdd(&cnt[i2], 1);
    toklist[i2 * NTOK + s2] = tok; wlist[i2 * NTOK + s2] = v2 * inv;
    atomicAdd(&sF[i1], 1);
  }
  __syncthreads();
  if (tid < NE) { atomicAdd(&Psum[tid], sP[tid]); atomicAdd(&fcnt[tid], sF[tid]); }
}

// ---------------- prefix-sum of counts + aux loss -------------
__global__ void k_scan_aux(const int* __restrict__ cnt, const int* __restrict__ fcnt,
                           const float* __restrict__ Psum, int* __restrict__ offs,
                           float* __restrict__ aux_out) {
  if (threadIdx.x == 0) {
    int o = 0; float a = 0.f;
    for (int e = 0; e < NE; e++) { offs[e] = o; o += cnt[e]; a += (float)fcnt[e] * Psum[e]; }
    aux_out[0] = 8.f * a / (4096.f * 4096.f);
  }
}

// ---------------- FFN pass 1: H = GELU(Xg @ W1 + b1), bf16 out -------------
__global__ __launch_bounds__(256) void k_ffn1(
    const unsigned short* __restrict__ xb, const unsigned short* __restrict__ w1t,
    const float* __restrict__ b1, const int* __restrict__ cnt,
    const int* __restrict__ offs, const int* __restrict__ toklist,
    unsigned short* __restrict__ H) {
  int e = blockIdx.z;
  int cn = cnt[e];
  int m0 = blockIdx.x * 128;
  if (m0 >= cn) return;
  int n0 = blockIdx.y * 128;
  __shared__ __align__(16) unsigned short At[128 * 64];
  __shared__ __align__(16) unsigned short Bt[128 * 64];
  int tid = threadIdx.x;
  int chunk = tid & 7, rsub = tid >> 3;
  const unsigned short* gA[4]; const unsigned short* gB[4];
  unsigned short* lA[4]; unsigned short* lB[4];
#pragma unroll
  for (int q = 0; q < 4; q++) {
    int row = q * 32 + rsub;
    int tr = m0 + row; if (tr >= cn) tr = cn - 1;   // clamp: garbage rows masked at store
    int tok = toklist[e * NTOK + tr];
    gA[q] = xb + (size_t)tok * DM + chunk * 8;
    gB[q] = w1t + ((size_t)e * DFF + n0 + row) * DM + chunk * 8;
    lA[q] = At + row * 64 + chunk * 8;   // == wave-uniform base + lane*16B
    lB[q] = Bt + row * 64 + chunk * 8;
  }
  int wid = tid >> 6, lane = tid & 63;
  int mW = (wid >> 1) * 64, nW = (wid & 1) * 64;
  int lr = lane & 15, quad = lane >> 4;
  f32x4 acc[4][4];
#pragma unroll
  for (int i = 0; i < 4; i++)
#pragma unroll
    for (int j = 0; j < 4; j++) acc[i][j] = (f32x4)(0.f);
  for (int k0 = 0; k0 < DM; k0 += 64) {
#pragma unroll
    for (int q = 0; q < 4; q++) async16(gA[q] + k0, lA[q]);
#pragma unroll
    for (int q = 0; q < 4; q++) async16(gB[q] + k0, lB[q]);
    __syncthreads();
#pragma unroll
    for (int kk = 0; kk < 64; kk += 32) {
      bf16x8 a[4], b[4];
#pragma unroll
      for (int i = 0; i < 4; i++) a[i] = *(const bf16x8*)(At + (mW + i * 16 + lr) * 64 + kk + quad * 8);
#pragma unroll
      for (int j = 0; j < 4; j++) b[j] = *(const bf16x8*)(Bt + (nW + j * 16 + lr) * 64 + kk + quad * 8);
#pragma unroll
      for (int i = 0; i < 4; i++)
#pragma unroll
        for (int j = 0; j < 4; j++)
          acc[i][j] = __builtin_amdgcn_mfma_f32_16x16x32_bf16(a[i], b[j], acc[i][j], 0, 0, 0);
    }
    __syncthreads();
  }
  int off = offs[e];
#pragma unroll
  for (int i = 0; i < 4; i++) {
#pragma unroll
    for (int r = 0; r < 4; r++) {
      int gr = m0 + mW + i * 16 + quad * 4 + r;   // C/D: row = quad*4+reg
      if (gr < cn) {
        size_t base = (size_t)(off + gr) * DFF + n0;
#pragma unroll
        for (int j = 0; j < 4; j++) {
          int col = nW + j * 16 + lr;             // C/D: col = lane&15
          float v = acc[i][j][r] + b1[(size_t)e * DFF + n0 + col];
          float g = 0.5f * v * (1.f + erff(v * 0.70710678f));  // exact-erf GELU
          H[base + col] = f2bf(g);
        }
      }
    }
  }
}

// ---------------- FFN pass 2: Y = H @ W2 + b2, scatter-add w*Y into out -------------
__global__ __launch_bounds__(256) void k_ffn2(
    const unsigned short* __restrict__ H, const unsigned short* __restrict__ w2t,
    const float* __restrict__ b2, const int* __restrict__ cnt,
    const int* __restrict__ offs, const int* __restrict__ toklist,
    const float* __restrict__ wlist, float* __restrict__ out) {
  int e = blockIdx.z;
  int cn = cnt[e];
  int m0 = blockIdx.x * 128;
  if (m0 >= cn) return;
  int n0 = blockIdx.y * 128;
  int off = offs[e];
  __shared__ __align__(16) unsigned short At[128 * 64];
  __shared__ __align__(16) unsigned short Bt[128 * 64];
  int tid = threadIdx.x;
  int chunk = tid & 7, rsub = tid >> 3;
  const unsigned short* gA[4]; const unsigned short* gB[4];
  unsigned short* lA[4]; unsigned short* lB[4];
#pragma unroll
  for (int q = 0; q < 4; q++) {
    int row = q * 32 + rsub;
    int hr = m0 + row; if (hr >= cn) hr = cn - 1;
    gA[q] = H + (size_t)(off + hr) * DFF + chunk * 8;
    gB[q] = w2t + ((size_t)e * DM + n0 + row) * DFF + chunk * 8;
    lA[q] = At + row * 64 + chunk * 8;
    lB[q] = Bt + row * 64 + chunk * 8;
  }
  int wid = tid >> 6, lane = tid & 63;
  int mW = (wid >> 1) * 64, nW = (wid & 1) * 64;
  int lr = lane & 15, quad = lane >> 4;
  f32x4 acc[4][4];
#pragma unroll
  for (int i = 0; i < 4; i++)
#pragma unroll
    for (int j = 0; j < 4; j++) acc[i][j] = (f32x4)(0.f);
  for (int k0 = 0; k0 < DFF; k0 += 64) {
#pragma unroll
    for (int q = 0; q < 4; q++) async16(gA[q] + k0, lA[q]);
#pragma unroll
    for (int q = 0; q < 4; q++) async16(gB[q] + k0, lB[q]);
    __syncthreads();
#pragma unroll
    for (int kk = 0; kk < 64; kk += 32) {
      bf16x8 a[4], b[4];
#pragma unroll
      for (int i = 0; i < 4; i++) a[i] = *(const bf16x8*)(At + (mW + i * 16 + lr) * 64 + kk + quad * 8);
#pragma unroll
      for (int j = 0; j < 4; j++) b[j] = *(const bf16x8*)(Bt + (nW + j * 16 + lr) * 64 + kk + quad * 8);
#pragma unroll
      for (int i = 0; i < 4; i++)
#pragma unroll
        for (int j = 0; j < 4; j++)
          acc[i][j] = __builtin_amdgcn_mfma_f32_16x16x32_bf16(a[i], b[j], acc[i][j], 0, 0, 0);
    }
    __syncthreads();
  }
#pragma unroll
  for (int i = 0; i < 4; i++) {
#pragma unroll
    for (int r = 0; r < 4; r++) {
      int gr = m0 + mW + i * 16 + quad * 4 + r;
      if (gr < cn) {
        int tok = toklist[e * NTOK + gr];
        float w = wlist[e * NTOK + gr];
#pragma unroll
        for (int j = 0; j < 4; j++) {
          int col = n0 + nW + j * 16 + lr;
          // exactly 2 adds per out element (one per selected expert): deterministic
          atomicAdd(&out[(size_t)tok * DM + col], w * (acc[i][j][r] + b2[(size_t)e * DM + col]));
        }
      }
    }
  }
}

__global__ void k_wsfail(float* out, float v) { if (threadIdx.x == 0) out[0] = v; }

extern "C" void kernel_launch(void* const* d_in, const int* in_sizes, int n_in,
                              void* d_out, int out_size, void* d_ws, size_t ws_size,
                              hipStream_t stream) {
  const float* x  = (const float*)d_in[0];
  const float* Wr = (const float*)d_in[1];
  const float* br = (const float*)d_in[2];
  const float* W1 = (const float*)d_in[3];
  const float* b1 = (const float*)d_in[4];
  const float* W2 = (const float*)d_in[5];
  const float* b2 = (const float*)d_in[6];
  float* out = (float*)d_out;
  char* ws = (char*)d_ws;

  // ws layout (MiB = 1<<20):
  //  [0,1024)        : cnt[8] @0, fcnt[8] @64, Psum[8] @128, offs[8] @192
  //  [1024, +128K)   : toklist int[8*4096]
  //  [+128K, +256K)  : wlist float[8*4096]
  //  [1M, 10M)       : x bf16      (8 MiB)
  //  [10M, 80M)      : W1^T bf16   (64 MiB)
  //  [80M, 144M)     : W2^T bf16   (64 MiB)
  //  [144M, 208M)    : H bf16      (64 MiB, 8192 x 4096)
  const size_t NEED = ((size_t)144 << 20) + (size_t)8192 * DFF * 2;
  if (ws_size < NEED) {  // debug beacon: absmax ~= ws_size as float
    hipLaunchKernelGGL(k_wsfail, dim3(1), dim3(64), 0, stream, out, (float)ws_size);
    return;
  }
  int* cnt      = (int*)(ws + 0);
  int* fcnt     = (int*)(ws + 64);
  float* Psum   = (float*)(ws + 128);
  int* offs     = (int*)(ws + 192);
  int* toklist  = (int*)(ws + 1024);
  float* wlist  = (float*)(ws + 1024 + 131072);
  unsigned short* xb  = (unsigned short*)(ws + ((size_t)1 << 20));
  unsigned short* w1t = (unsigned short*)(ws + ((size_t)10 << 20));
  unsigned short* w2t = (unsigned short*)(ws + ((size_t)80 << 20));
  unsigned short* Hb  = (unsigned short*)(ws + ((size_t)144 << 20));

  hipMemsetAsync(d_out, 0, (size_t)out_size * sizeof(float), stream);  // out accumulated via atomics
  hipMemsetAsync(ws, 0, 1024, stream);                                  // zero counters

  hipLaunchKernelGGL(k_cvt_x, dim3(NTOK * DM / 1024), dim3(256), 0, stream, x, xb);
  hipLaunchKernelGGL(k_transpose_bf, dim3(DFF / 32, DM / 32, NE), dim3(32, 8), 0, stream, W1, w1t, DM, DFF);
  hipLaunchKernelGGL(k_transpose_bf, dim3(DM / 32, DFF / 32, NE), dim3(32, 8), 0, stream, W2, w2t, DFF, DM);
  hipLaunchKernelGGL(k_router, dim3(NTOK / 32), dim3(256), 0, stream, x, Wr, br, cnt, fcnt, Psum, toklist, wlist);
  hipLaunchKernelGGL(k_scan_aux, dim3(1), dim3(64), 0, stream, cnt, fcnt, Psum, offs, out + (out_size - 1));
  hipLaunchKernelGGL(k_ffn1, dim3(32, DFF / 128, NE), dim3(256), 0, stream, xb, w1t, b1, cnt, offs, toklist, Hb);
  hipLaunchKernelGGL(k_ffn2, dim3(32, DM / 128, NE), dim3(256), 0, stream, Hb, w2t, b2, cnt, offs, toklist, wlist, out);
}

// Round 2
// 741.261 us; speedup vs baseline: 2.0275x; 2.0275x over previous
//
#include <hip/hip_runtime.h>
#include <cstdint>
#include <cstddef>

#define NTOK 4096   // B*S = 2*2048
#define DM   1024   // D_MODEL
#define DFF  4096   // D_FF
#define NE   8      // experts
#define MAXTILES 72 // >= sum_e ceil(cnt[e]/128), worst case 64+7

typedef __attribute__((ext_vector_type(8))) __bf16 bf16x8;
typedef __attribute__((ext_vector_type(4))) float  f32x4;

// round-to-nearest-even fp32 -> bf16
__device__ __forceinline__ unsigned short f2bf(float f) {
  union { float f; unsigned int u; } c; c.f = f;
  unsigned int u = c.u;
  return (unsigned short)((u + 0x7fffu + ((u >> 16) & 1u)) >> 16);
}

// async global->LDS, 16B per lane (global_load_lds_dwordx4)
__device__ __forceinline__ void async16(const void* g, void* l) {
  __builtin_amdgcn_global_load_lds(
      (const __attribute__((address_space(1))) void*)(uintptr_t)g,
      (__attribute__((address_space(3))) void*)(uint32_t)(uintptr_t)l,
      16, 0, 0);
}

// ---------------- x fp32 -> bf16 ----------------
__global__ void k_cvt_x(const float* __restrict__ x, unsigned short* __restrict__ xb) {
  int i = (blockIdx.x * 256 + threadIdx.x) * 4;
  float4 v = *(const float4*)(x + i);
  ushort4 o;
  o.x = f2bf(v.x); o.y = f2bf(v.y); o.z = f2bf(v.z); o.w = f2bf(v.w);
  *(ushort4*)(xb + i) = o;
}

// ---------------- transpose + convert: src[R][C] fp32 -> dst[C][R] bf16 (per expert z) ----
__global__ void k_transpose_bf(const float* __restrict__ src, unsigned short* __restrict__ dst,
                               int R, int C) {
  __shared__ float tile[32][33];
  int e = blockIdx.z;
  src += (size_t)e * R * C;
  dst += (size_t)e * R * C;
  int tx = threadIdx.x, ty = threadIdx.y;
  int c = blockIdx.x * 32 + tx;
#pragma unroll
  for (int q = 0; q < 4; q++) {
    int r = blockIdx.y * 32 + q * 8 + ty;
    tile[q * 8 + ty][tx] = src[(size_t)r * C + c];
  }
  __syncthreads();
#pragma unroll
  for (int q = 0; q < 4; q++) {
    dst[(size_t)(blockIdx.x * 32 + q * 8 + ty) * R + blockIdx.y * 32 + tx] =
        f2bf(tile[tx][q * 8 + ty]);
  }
}

// ---------------- router: logits, softmax, top-2, aux stats, token lists -------------
__global__ void k_router(const float* __restrict__ x, const float* __restrict__ Wr,
                         const float* __restrict__ br, int* __restrict__ cnt,
                         int* __restrict__ fcnt, float* __restrict__ Psum,
                         int* __restrict__ toklist, float* __restrict__ wlist) {
  __shared__ float sP[NE];
  __shared__ int sF[NE];
  int tid = threadIdx.x;
  if (tid < NE) { sP[tid] = 0.f; sF[tid] = 0; }
  __syncthreads();
  int tok = blockIdx.x * 32 + (tid >> 3);  // 8 lanes per token, 32 tokens/block
  int e = tid & 7;
  const float* xr = x + (size_t)tok * DM;
  float acc = 0.f;
#pragma unroll 4
  for (int i = 0; i < DM; i += 4) {
    float4 xv = *(const float4*)(xr + i);
    acc = fmaf(xv.x, Wr[(i + 0) * NE + e], acc);
    acc = fmaf(xv.y, Wr[(i + 1) * NE + e], acc);
    acc = fmaf(xv.z, Wr[(i + 2) * NE + e], acc);
    acc = fmaf(xv.w, Wr[(i + 3) * NE + e], acc);
  }
  acc += br[e];
  // softmax over the 8-lane group (group stays inside one 64-lane wave)
  float m = acc;
  for (int s = 1; s < 8; s <<= 1) m = fmaxf(m, __shfl_xor(m, s));
  float p = expf(acc - m);
  float sum = p;
  for (int s = 1; s < 8; s <<= 1) sum += __shfl_xor(sum, s);
  float prob = p / sum;
  atomicAdd(&sP[e], prob);
  int lanebase = (tid & 63) & ~7;
  float pv[8];
#pragma unroll
  for (int j = 0; j < 8; j++) pv[j] = __shfl(prob, lanebase + j);
  if (e == 0) {
    // top-1 (== argmax for f-histogram); ties -> lowest index, matching jax
    int i1 = 0; float v1 = pv[0];
#pragma unroll
    for (int j = 1; j < 8; j++) if (pv[j] > v1) { v1 = pv[j]; i1 = j; }
    int i2 = -1; float v2 = -1.f;
#pragma unroll
    for (int j = 0; j < 8; j++) if (j != i1 && pv[j] > v2) { v2 = pv[j]; i2 = j; }
    float inv = 1.f / (v1 + v2);
    int s1 = atomicAdd(&cnt[i1], 1);
    toklist[i1 * NTOK + s1] = tok; wlist[i1 * NTOK + s1] = v1 * inv;
    int s2 = atomicAdd(&cnt[i2], 1);
    toklist[i2 * NTOK + s2] = tok; wlist[i2 * NTOK + s2] = v2 * inv;
    atomicAdd(&sF[i1], 1);
  }
  __syncthreads();
  if (tid < NE) { atomicAdd(&Psum[tid], sP[tid]); atomicAdd(&fcnt[tid], sF[tid]); }
}

// ---------------- prefix-sum, aux loss, dense tile table -------------
__global__ void k_scan_aux(const int* __restrict__ cnt, const int* __restrict__ fcnt,
                           const float* __restrict__ Psum, int* __restrict__ offs,
                           int* __restrict__ ntiles, int* __restrict__ tileE,
                           int* __restrict__ tileM0, float* __restrict__ aux_out) {
  if (threadIdx.x == 0) {
    int o = 0; float a = 0.f; int t = 0;
    for (int e = 0; e < NE; e++) {
      offs[e] = o; o += cnt[e];
      a += (float)fcnt[e] * Psum[e];
      for (int m0 = 0; m0 < cnt[e]; m0 += 128) { tileE[t] = e; tileM0[t] = m0; t++; }
    }
    *ntiles = t;
    aux_out[0] = 8.f * a / (4096.f * 4096.f);
  }
}

// ---------------- FFN pass 1: H = GELU(Xg @ W1 + b1), bf16 out -------------
// LDS chunk order XOR-swizzled by (row&7): conflict-free fragment reads,
// staging stays lane-linear (global_load_lds requirement).
__global__ __launch_bounds__(256) void k_ffn1(
    const unsigned short* __restrict__ xb, const unsigned short* __restrict__ w1t,
    const float* __restrict__ b1, const int* __restrict__ cnt,
    const int* __restrict__ offs, const int* __restrict__ ntiles,
    const int* __restrict__ tileE, const int* __restrict__ tileM0,
    const int* __restrict__ toklist, unsigned short* __restrict__ H) {
  int t = blockIdx.x;
  if (t >= *ntiles) return;
  int e = tileE[t], m0 = tileM0[t];
  int cn = cnt[e];
  int n0 = blockIdx.y * 128;
  __shared__ __align__(16) unsigned short At[128 * 64];
  __shared__ __align__(16) unsigned short Bt[128 * 64];
  int tid = threadIdx.x;
  int chunk = tid & 7, rsub = tid >> 3;
  int cg = (chunk ^ (rsub & 7)) * 8;      // swizzled source chunk (shorts)
  const unsigned short* gA[4]; const unsigned short* gB[4];
  unsigned short* lA[4]; unsigned short* lB[4];
#pragma unroll
  for (int q = 0; q < 4; q++) {
    int row = q * 32 + rsub;
    int tr = m0 + row; if (tr >= cn) tr = cn - 1;   // clamp: garbage rows masked at store
    int tok = toklist[e * NTOK + tr];
    gA[q] = xb + (size_t)tok * DM + cg;
    gB[q] = w1t + ((size_t)e * DFF + n0 + row) * DM + cg;
    lA[q] = At + row * 64 + chunk * 8;   // wave-uniform base + lane*16B
    lB[q] = Bt + row * 64 + chunk * 8;
  }
  int wid = tid >> 6, lane = tid & 63;
  int mW = (wid >> 1) * 64, nW = (wid & 1) * 64;
  int lr = lane & 15, quad = lane >> 4;
  int sw = lane & 7;                      // == lr & 7
  f32x4 acc[4][4];
#pragma unroll
  for (int i = 0; i < 4; i++)
#pragma unroll
    for (int j = 0; j < 4; j++) acc[i][j] = (f32x4)(0.f);
  for (int k0 = 0; k0 < DM; k0 += 64) {
#pragma unroll
    for (int q = 0; q < 4; q++) async16(gA[q] + k0, lA[q]);
#pragma unroll
    for (int q = 0; q < 4; q++) async16(gB[q] + k0, lB[q]);
    __syncthreads();
#pragma unroll
    for (int kk8 = 0; kk8 < 8; kk8 += 4) {   // logical chunk base: 0 or 4
      int cs = ((kk8 + quad) ^ sw) * 8;      // swizzled chunk offset (shorts)
      bf16x8 a[4], b[4];
#pragma unroll
      for (int i = 0; i < 4; i++) a[i] = *(const bf16x8*)(At + (mW + i * 16 + lr) * 64 + cs);
#pragma unroll
      for (int j = 0; j < 4; j++) b[j] = *(const bf16x8*)(Bt + (nW + j * 16 + lr) * 64 + cs);
#pragma unroll
      for (int i = 0; i < 4; i++)
#pragma unroll
        for (int j = 0; j < 4; j++)
          acc[i][j] = __builtin_amdgcn_mfma_f32_16x16x32_bf16(a[i], b[j], acc[i][j], 0, 0, 0);
    }
    __syncthreads();
  }
  int off = offs[e];
#pragma unroll
  for (int i = 0; i < 4; i++) {
#pragma unroll
    for (int r = 0; r < 4; r++) {
      int gr = m0 + mW + i * 16 + quad * 4 + r;   // C/D: row = quad*4+reg
      if (gr < cn) {
        size_t base = (size_t)(off + gr) * DFF + n0;
#pragma unroll
        for (int j = 0; j < 4; j++) {
          int col = nW + j * 16 + lr;             // C/D: col = lane&15
          float v = acc[i][j][r] + b1[(size_t)e * DFF + n0 + col];
          float g = 0.5f * v * (1.f + erff(v * 0.70710678f));  // exact-erf GELU
          H[base + col] = f2bf(g);
        }
      }
    }
  }
}

// ---------------- FFN pass 2: Y = H @ W2 + b2, scatter-add w*Y, split-K=2 -------------
__global__ __launch_bounds__(256) void k_ffn2(
    const unsigned short* __restrict__ H, const unsigned short* __restrict__ w2t,
    const float* __restrict__ b2, const int* __restrict__ cnt,
    const int* __restrict__ offs, const int* __restrict__ ntiles,
    const int* __restrict__ tileE, const int* __restrict__ tileM0,
    const int* __restrict__ toklist, const float* __restrict__ wlist,
    float* __restrict__ out) {
  int t = blockIdx.x;
  if (t >= *ntiles) return;
  int e = tileE[t], m0 = tileM0[t];
  int cn = cnt[e];
  int n0 = blockIdx.y * 128;
  int kz = blockIdx.z;                    // split-K half: [kz*2048, kz*2048+2048)
  int off = offs[e];
  __shared__ __align__(16) unsigned short At[128 * 64];
  __shared__ __align__(16) unsigned short Bt[128 * 64];
  int tid = threadIdx.x;
  int chunk = tid & 7, rsub = tid >> 3;
  int cg = (chunk ^ (rsub & 7)) * 8;
  const unsigned short* gA[4]; const unsigned short* gB[4];
  unsigned short* lA[4]; unsigned short* lB[4];
#pragma unroll
  for (int q = 0; q < 4; q++) {
    int row = q * 32 + rsub;
    int hr = m0 + row; if (hr >= cn) hr = cn - 1;
    gA[q] = H + (size_t)(off + hr) * DFF + cg;
    gB[q] = w2t + ((size_t)e * DM + n0 + row) * DFF + cg;
    lA[q] = At + row * 64 + chunk * 8;
    lB[q] = Bt + row * 64 + chunk * 8;
  }
  int wid = tid >> 6, lane = tid & 63;
  int mW = (wid >> 1) * 64, nW = (wid & 1) * 64;
  int lr = lane & 15, quad = lane >> 4;
  int sw = lane & 7;
  f32x4 acc[4][4];
#pragma unroll
  for (int i = 0; i < 4; i++)
#pragma unroll
    for (int j = 0; j < 4; j++) acc[i][j] = (f32x4)(0.f);
  int kbeg = kz * (DFF / 2), kend = kbeg + DFF / 2;
  for (int k0 = kbeg; k0 < kend; k0 += 64) {
#pragma unroll
    for (int q = 0; q < 4; q++) async16(gA[q] + k0, lA[q]);
#pragma unroll
    for (int q = 0; q < 4; q++) async16(gB[q] + k0, lB[q]);
    __syncthreads();
#pragma unroll
    for (int kk8 = 0; kk8 < 8; kk8 += 4) {
      int cs = ((kk8 + quad) ^ sw) * 8;
      bf16x8 a[4], b[4];
#pragma unroll
      for (int i = 0; i < 4; i++) a[i] = *(const bf16x8*)(At + (mW + i * 16 + lr) * 64 + cs);
#pragma unroll
      for (int j = 0; j < 4; j++) b[j] = *(const bf16x8*)(Bt + (nW + j * 16 + lr) * 64 + cs);
#pragma unroll
      for (int i = 0; i < 4; i++)
#pragma unroll
        for (int j = 0; j < 4; j++)
          acc[i][j] = __builtin_amdgcn_mfma_f32_16x16x32_bf16(a[i], b[j], acc[i][j], 0, 0, 0);
    }
    __syncthreads();
  }
#pragma unroll
  for (int i = 0; i < 4; i++) {
#pragma unroll
    for (int r = 0; r < 4; r++) {
      int gr = m0 + mW + i * 16 + quad * 4 + r;
      if (gr < cn) {
        int tok = toklist[e * NTOK + gr];
        float w = wlist[e * NTOK + gr];
#pragma unroll
        for (int j = 0; j < 4; j++) {
          int col = n0 + nW + j * 16 + lr;
          float v = acc[i][j][r] + (kz == 0 ? b2[(size_t)e * DM + col] : 0.f);
          atomicAdd(&out[(size_t)tok * DM + col], w * v);
        }
      }
    }
  }
}

__global__ void k_wsfail(float* out, float v) { if (threadIdx.x == 0) out[0] = v; }

extern "C" void kernel_launch(void* const* d_in, const int* in_sizes, int n_in,
                              void* d_out, int out_size, void* d_ws, size_t ws_size,
                              hipStream_t stream) {
  const float* x  = (const float*)d_in[0];
  const float* Wr = (const float*)d_in[1];
  const float* br = (const float*)d_in[2];
  const float* W1 = (const float*)d_in[3];
  const float* b1 = (const float*)d_in[4];
  const float* W2 = (const float*)d_in[5];
  const float* b2 = (const float*)d_in[6];
  float* out = (float*)d_out;
  char* ws = (char*)d_ws;

  // ws layout:
  //  [0,4096)      : cnt@0 fcnt@64 Psum@128 offs@192 ntiles@256 tileE@512 tileM0@1024
  //  [4096,+128K)  : toklist int[8*4096]   @4096
  //  then wlist float[8*4096]              @4096+128K
  //  [1M, 10M)     : x bf16 ; [10M,80M) W1^T ; [80M,144M) W2^T ; [144M,208M) H
  const size_t NEED = ((size_t)144 << 20) + (size_t)8192 * DFF * 2;
  if (ws_size < NEED) {
    hipLaunchKernelGGL(k_wsfail, dim3(1), dim3(64), 0, stream, out, (float)ws_size);
    return;
  }
  int* cnt      = (int*)(ws + 0);
  int* fcnt     = (int*)(ws + 64);
  float* Psum   = (float*)(ws + 128);
  int* offs     = (int*)(ws + 192);
  int* ntiles   = (int*)(ws + 256);
  int* tileE    = (int*)(ws + 512);
  int* tileM0   = (int*)(ws + 1024);
  int* toklist  = (int*)(ws + 4096);
  float* wlist  = (float*)(ws + 4096 + 131072);
  unsigned short* xb  = (unsigned short*)(ws + ((size_t)1 << 20));
  unsigned short* w1t = (unsigned short*)(ws + ((size_t)10 << 20));
  unsigned short* w2t = (unsigned short*)(ws + ((size_t)80 << 20));
  unsigned short* Hb  = (unsigned short*)(ws + ((size_t)144 << 20));

  hipMemsetAsync(d_out, 0, (size_t)out_size * sizeof(float), stream);
  hipMemsetAsync(ws, 0, 4096, stream);

  hipLaunchKernelGGL(k_cvt_x, dim3(NTOK * DM / 1024), dim3(256), 0, stream, x, xb);
  hipLaunchKernelGGL(k_transpose_bf, dim3(DFF / 32, DM / 32, NE), dim3(32, 8), 0, stream, W1, w1t, DM, DFF);
  hipLaunchKernelGGL(k_transpose_bf, dim3(DM / 32, DFF / 32, NE), dim3(32, 8), 0, stream, W2, w2t, DFF, DM);
  hipLaunchKernelGGL(k_router, dim3(NTOK / 32), dim3(256), 0, stream, x, Wr, br, cnt, fcnt, Psum, toklist, wlist);
  hipLaunchKernelGGL(k_scan_aux, dim3(1), dim3(64), 0, stream, cnt, fcnt, Psum, offs, ntiles, tileE, tileM0, out + (out_size - 1));
  hipLaunchKernelGGL(k_ffn1, dim3(MAXTILES, DFF / 128), dim3(256), 0, stream,
                     xb, w1t, b1, cnt, offs, ntiles, tileE, tileM0, toklist, Hb);
  hipLaunchKernelGGL(k_ffn2, dim3(MAXTILES, DM / 128, 2), dim3(256), 0, stream,
                     Hb, w2t, b2, cnt, offs, ntiles, tileE, tileM0, toklist, wlist, out);
}

// Round 3
// 652.175 us; speedup vs baseline: 2.3045x; 1.1366x over previous
//
#include <hip/hip_runtime.h>
#include <cstdint>
#include <cstddef>

#define NTOK 4096   // B*S = 2*2048
#define DM   1024   // D_MODEL
#define DFF  4096   // D_FF
#define NE   8      // experts
#define MAXTILES 72 // >= sum_e ceil(cnt[e]/128), worst case 64+7

typedef __attribute__((ext_vector_type(8))) __bf16 bf16x8;
typedef __attribute__((ext_vector_type(4))) float  f32x4;

// round-to-nearest-even fp32 -> bf16
__device__ __forceinline__ unsigned short f2bf(float f) {
  union { float f; unsigned int u; } c; c.f = f;
  unsigned int u = c.u;
  return (unsigned short)((u + 0x7fffu + ((u >> 16) & 1u)) >> 16);
}

// async global->LDS, 16B per lane (global_load_lds_dwordx4)
__device__ __forceinline__ void async16(const void* g, void* l) {
  __builtin_amdgcn_global_load_lds(
      (const __attribute__((address_space(1))) void*)(uintptr_t)g,
      (__attribute__((address_space(3))) void*)(uint32_t)(uintptr_t)l,
      16, 0, 0);
}

// exact-erf GELU via Abramowitz-Stegun 7.1.26 (|err| < 1.5e-7, ~14 VALU ops)
__device__ __forceinline__ float gelu_erf(float v) {
  float u = v * 0.70710678118f;
  float az = fabsf(u);
  float t = __builtin_amdgcn_rcpf(fmaf(0.3275911f, az, 1.f));
  float p = fmaf(1.061405429f, t, -1.453152027f);
  p = fmaf(p, t, 1.421413741f);
  p = fmaf(p, t, -0.284496736f);
  p = fmaf(p, t, 0.254829592f);
  p = p * t;
  float ex = __builtin_amdgcn_exp2f(-az * az * 1.44269504089f);
  float er = fmaf(-p, ex, 1.f);
  er = copysignf(er, u);
  return 0.5f * v * (1.f + er);
}

// ---------------- x fp32 -> bf16 ----------------
__global__ void k_cvt_x(const float* __restrict__ x, unsigned short* __restrict__ xb) {
  int i = (blockIdx.x * 256 + threadIdx.x) * 4;
  float4 v = *(const float4*)(x + i);
  ushort4 o;
  o.x = f2bf(v.x); o.y = f2bf(v.y); o.z = f2bf(v.z); o.w = f2bf(v.w);
  *(ushort4*)(xb + i) = o;
}

// ---------------- transpose + convert: src[R][C] fp32 -> dst[C][R] bf16 (per expert z) ----
__global__ void k_transpose_bf(const float* __restrict__ src, unsigned short* __restrict__ dst,
                               int R, int C) {
  __shared__ float tile[32][33];
  int e = blockIdx.z;
  src += (size_t)e * R * C;
  dst += (size_t)e * R * C;
  int tx = threadIdx.x, ty = threadIdx.y;
  int c = blockIdx.x * 32 + tx;
#pragma unroll
  for (int q = 0; q < 4; q++) {
    int r = blockIdx.y * 32 + q * 8 + ty;
    tile[q * 8 + ty][tx] = src[(size_t)r * C + c];
  }
  __syncthreads();
#pragma unroll
  for (int q = 0; q < 4; q++) {
    dst[(size_t)(blockIdx.x * 32 + q * 8 + ty) * R + blockIdx.y * 32 + tx] =
        f2bf(tile[tx][q * 8 + ty]);
  }
}

// ---------------- router: logits, softmax, top-2, aux stats, token lists + inverse map ----
__global__ void k_router(const float* __restrict__ x, const float* __restrict__ Wr,
                         const float* __restrict__ br, int* __restrict__ cnt,
                         int* __restrict__ fcnt, float* __restrict__ Psum,
                         int* __restrict__ toklist, float* __restrict__ wlist,
                         int* __restrict__ tokmap, float* __restrict__ tokw) {
  __shared__ float sP[NE];
  __shared__ int sF[NE];
  int tid = threadIdx.x;
  if (tid < NE) { sP[tid] = 0.f; sF[tid] = 0; }
  __syncthreads();
  int tok = blockIdx.x * 32 + (tid >> 3);  // 8 lanes per token, 32 tokens/block
  int e = tid & 7;
  const float* xr = x + (size_t)tok * DM;
  float acc = 0.f;
#pragma unroll 4
  for (int i = 0; i < DM; i += 4) {
    float4 xv = *(const float4*)(xr + i);
    acc = fmaf(xv.x, Wr[(i + 0) * NE + e], acc);
    acc = fmaf(xv.y, Wr[(i + 1) * NE + e], acc);
    acc = fmaf(xv.z, Wr[(i + 2) * NE + e], acc);
    acc = fmaf(xv.w, Wr[(i + 3) * NE + e], acc);
  }
  acc += br[e];
  // softmax over the 8-lane group (group stays inside one 64-lane wave)
  float m = acc;
  for (int s = 1; s < 8; s <<= 1) m = fmaxf(m, __shfl_xor(m, s));
  float p = expf(acc - m);
  float sum = p;
  for (int s = 1; s < 8; s <<= 1) sum += __shfl_xor(sum, s);
  float prob = p / sum;
  atomicAdd(&sP[e], prob);
  int lanebase = (tid & 63) & ~7;
  float pv[8];
#pragma unroll
  for (int j = 0; j < 8; j++) pv[j] = __shfl(prob, lanebase + j);
  if (e == 0) {
    // top-1 (== argmax for f-histogram); ties -> lowest index, matching jax
    int i1 = 0; float v1 = pv[0];
#pragma unroll
    for (int j = 1; j < 8; j++) if (pv[j] > v1) { v1 = pv[j]; i1 = j; }
    int i2 = -1; float v2 = -1.f;
#pragma unroll
    for (int j = 0; j < 8; j++) if (j != i1 && pv[j] > v2) { v2 = pv[j]; i2 = j; }
    float inv = 1.f / (v1 + v2);
    int s1 = atomicAdd(&cnt[i1], 1);
    toklist[i1 * NTOK + s1] = tok; wlist[i1 * NTOK + s1] = v1 * inv;
    int s2 = atomicAdd(&cnt[i2], 1);
    toklist[i2 * NTOK + s2] = tok; wlist[i2 * NTOK + s2] = v2 * inv;
    tokmap[tok * 2] = (i1 << 16) | s1;  tokw[tok * 2] = v1 * inv;
    tokmap[tok * 2 + 1] = (i2 << 16) | s2; tokw[tok * 2 + 1] = v2 * inv;
    atomicAdd(&sF[i1], 1);
  }
  __syncthreads();
  if (tid < NE) { atomicAdd(&Psum[tid], sP[tid]); atomicAdd(&fcnt[tid], sF[tid]); }
}

// ---------------- prefix-sum, aux loss, dense tile table -------------
__global__ void k_scan_aux(const int* __restrict__ cnt, const int* __restrict__ fcnt,
                           const float* __restrict__ Psum, int* __restrict__ offs,
                           int* __restrict__ ntiles, int* __restrict__ tileE,
                           int* __restrict__ tileM0, float* __restrict__ aux_out) {
  if (threadIdx.x == 0) {
    int o = 0; float a = 0.f; int t = 0;
    for (int e = 0; e < NE; e++) {
      offs[e] = o; o += cnt[e];
      a += (float)fcnt[e] * Psum[e];
      for (int m0 = 0; m0 < cnt[e]; m0 += 128) { tileE[t] = e; tileM0[t] = m0; t++; }
    }
    *ntiles = t;
    aux_out[0] = 8.f * a / (4096.f * 4096.f);
  }
}

// ---------------- FFN pass 1: H = GELU(Xg @ W1 + b1), bf16 out -------------
// grid (n-tile fast, token-tile slow): consecutive blocks share the A-tile.
__global__ __launch_bounds__(256) void k_ffn1(
    const unsigned short* __restrict__ xb, const unsigned short* __restrict__ w1t,
    const float* __restrict__ b1, const int* __restrict__ cnt,
    const int* __restrict__ offs, const int* __restrict__ ntiles,
    const int* __restrict__ tileE, const int* __restrict__ tileM0,
    const int* __restrict__ toklist, unsigned short* __restrict__ H) {
  int t = blockIdx.y;
  if (t >= *ntiles) return;
  int e = tileE[t], m0 = tileM0[t];
  int cn = cnt[e];
  int n0 = blockIdx.x * 128;
  __shared__ __align__(16) unsigned short At[128 * 64];
  __shared__ __align__(16) unsigned short Bt[128 * 64];
  int tid = threadIdx.x;
  int chunk = tid & 7, rsub = tid >> 3;
  int cg = (chunk ^ (rsub & 7)) * 8;      // swizzled source chunk (shorts)
  const unsigned short* gA[4]; const unsigned short* gB[4];
  unsigned short* lA[4]; unsigned short* lB[4];
#pragma unroll
  for (int q = 0; q < 4; q++) {
    int row = q * 32 + rsub;
    int tr = m0 + row; if (tr >= cn) tr = cn - 1;   // clamp: garbage rows masked at store
    int tok = toklist[e * NTOK + tr];
    gA[q] = xb + (size_t)tok * DM + cg;
    gB[q] = w1t + ((size_t)e * DFF + n0 + row) * DM + cg;
    lA[q] = At + row * 64 + chunk * 8;   // wave-uniform base + lane*16B
    lB[q] = Bt + row * 64 + chunk * 8;
  }
  int wid = tid >> 6, lane = tid & 63;
  int mW = (wid >> 1) * 64, nW = (wid & 1) * 64;
  int lr = lane & 15, quad = lane >> 4;
  int sw = lane & 7;                      // == lr & 7
  f32x4 acc[4][4];
#pragma unroll
  for (int i = 0; i < 4; i++)
#pragma unroll
    for (int j = 0; j < 4; j++) acc[i][j] = (f32x4)(0.f);
  for (int k0 = 0; k0 < DM; k0 += 64) {
#pragma unroll
    for (int q = 0; q < 4; q++) async16(gA[q] + k0, lA[q]);
#pragma unroll
    for (int q = 0; q < 4; q++) async16(gB[q] + k0, lB[q]);
    __syncthreads();
#pragma unroll
    for (int kk8 = 0; kk8 < 8; kk8 += 4) {   // logical chunk base: 0 or 4
      int cs = ((kk8 + quad) ^ sw) * 8;      // swizzled chunk offset (shorts)
      bf16x8 a[4], b[4];
#pragma unroll
      for (int i = 0; i < 4; i++) a[i] = *(const bf16x8*)(At + (mW + i * 16 + lr) * 64 + cs);
#pragma unroll
      for (int j = 0; j < 4; j++) b[j] = *(const bf16x8*)(Bt + (nW + j * 16 + lr) * 64 + cs);
#pragma unroll
      for (int i = 0; i < 4; i++)
#pragma unroll
        for (int j = 0; j < 4; j++)
          acc[i][j] = __builtin_amdgcn_mfma_f32_16x16x32_bf16(a[i], b[j], acc[i][j], 0, 0, 0);
    }
    __syncthreads();
  }
  int off = offs[e];
#pragma unroll
  for (int i = 0; i < 4; i++) {
#pragma unroll
    for (int r = 0; r < 4; r++) {
      int gr = m0 + mW + i * 16 + quad * 4 + r;   // C/D: row = quad*4+reg
      if (gr < cn) {
        size_t base = (size_t)(off + gr) * DFF + n0;
#pragma unroll
        for (int j = 0; j < 4; j++) {
          int col = nW + j * 16 + lr;             // C/D: col = lane&15
          float v = acc[i][j][r] + b1[(size_t)e * DFF + n0 + col];
          H[base + col] = f2bf(gelu_erf(v));
        }
      }
    }
  }
}

// ---------------- FFN pass 2: P[kz] = Hg @ W2 partials (no bias/weight), split-K=2 ----
__global__ __launch_bounds__(256) void k_ffn2(
    const unsigned short* __restrict__ H, const unsigned short* __restrict__ w2t,
    const int* __restrict__ cnt, const int* __restrict__ offs,
    const int* __restrict__ ntiles, const int* __restrict__ tileE,
    const int* __restrict__ tileM0, float* __restrict__ P) {
  int t = blockIdx.y;
  if (t >= *ntiles) return;
  int e = tileE[t], m0 = tileM0[t];
  int cn = cnt[e];
  int n0 = blockIdx.x * 128;
  int kz = blockIdx.z;                    // split-K half: [kz*2048, kz*2048+2048)
  int off = offs[e];
  __shared__ __align__(16) unsigned short At[128 * 64];
  __shared__ __align__(16) unsigned short Bt[128 * 64];
  int tid = threadIdx.x;
  int chunk = tid & 7, rsub = tid >> 3;
  int cg = (chunk ^ (rsub & 7)) * 8;
  const unsigned short* gA[4]; const unsigned short* gB[4];
  unsigned short* lA[4]; unsigned short* lB[4];
#pragma unroll
  for (int q = 0; q < 4; q++) {
    int row = q * 32 + rsub;
    int hr = m0 + row; if (hr >= cn) hr = cn - 1;
    gA[q] = H + (size_t)(off + hr) * DFF + cg;
    gB[q] = w2t + ((size_t)e * DM + n0 + row) * DFF + cg;
    lA[q] = At + row * 64 + chunk * 8;
    lB[q] = Bt + row * 64 + chunk * 8;
  }
  int wid = tid >> 6, lane = tid & 63;
  int mW = (wid >> 1) * 64, nW = (wid & 1) * 64;
  int lr = lane & 15, quad = lane >> 4;
  int sw = lane & 7;
  f32x4 acc[4][4];
#pragma unroll
  for (int i = 0; i < 4; i++)
#pragma unroll
    for (int j = 0; j < 4; j++) acc[i][j] = (f32x4)(0.f);
  int kbeg = kz * (DFF / 2), kend = kbeg + DFF / 2;
  for (int k0 = kbeg; k0 < kend; k0 += 64) {
#pragma unroll
    for (int q = 0; q < 4; q++) async16(gA[q] + k0, lA[q]);
#pragma unroll
    for (int q = 0; q < 4; q++) async16(gB[q] + k0, lB[q]);
    __syncthreads();
#pragma unroll
    for (int kk8 = 0; kk8 < 8; kk8 += 4) {
      int cs = ((kk8 + quad) ^ sw) * 8;
      bf16x8 a[4], b[4];
#pragma unroll
      for (int i = 0; i < 4; i++) a[i] = *(const bf16x8*)(At + (mW + i * 16 + lr) * 64 + cs);
#pragma unroll
      for (int j = 0; j < 4; j++) b[j] = *(const bf16x8*)(Bt + (nW + j * 16 + lr) * 64 + cs);
#pragma unroll
      for (int i = 0; i < 4; i++)
#pragma unroll
        for (int j = 0; j < 4; j++)
          acc[i][j] = __builtin_amdgcn_mfma_f32_16x16x32_bf16(a[i], b[j], acc[i][j], 0, 0, 0);
    }
    __syncthreads();
  }
  float* Pk = P + (size_t)kz * 8192 * DM;
#pragma unroll
  for (int i = 0; i < 4; i++) {
#pragma unroll
    for (int r = 0; r < 4; r++) {
      int gr = m0 + mW + i * 16 + quad * 4 + r;
      if (gr < cn) {
        size_t base = (size_t)(off + gr) * DM + n0;
#pragma unroll
        for (int j = 0; j < 4; j++) {
          int col = nW + j * 16 + lr;
          Pk[base + col] = acc[i][j][r];   // plain store: unique row per (token,expert)
        }
      }
    }
  }
}

// ---------------- combine: out[tok] = sum_s w_s * (P0[r_s] + P1[r_s] + b2[e_s]) ----------
__global__ __launch_bounds__(256) void k_combine(
    const float* __restrict__ P, const float* __restrict__ b2,
    const int* __restrict__ offs, const int* __restrict__ tokmap,
    const float* __restrict__ tokw, float* __restrict__ out) {
  int tok = blockIdx.x;
  int c4 = threadIdx.x * 4;
  int enc0 = tokmap[tok * 2], enc1 = tokmap[tok * 2 + 1];
  float w0 = tokw[tok * 2], w1 = tokw[tok * 2 + 1];
  int e0 = enc0 >> 16, p0 = enc0 & 0xffff;
  int e1 = enc1 >> 16, p1 = enc1 & 0xffff;
  size_t r0 = (size_t)(offs[e0] + p0) * DM;
  size_t r1 = (size_t)(offs[e1] + p1) * DM;
  const size_t KZ = (size_t)8192 * DM;
  float4 a0 = *(const float4*)(P + r0 + c4);
  float4 a1 = *(const float4*)(P + KZ + r0 + c4);
  float4 c0 = *(const float4*)(P + r1 + c4);
  float4 c1 = *(const float4*)(P + KZ + r1 + c4);
  float4 bb0 = *(const float4*)(b2 + (size_t)e0 * DM + c4);
  float4 bb1 = *(const float4*)(b2 + (size_t)e1 * DM + c4);
  float4 o;
  o.x = w0 * (a0.x + a1.x + bb0.x) + w1 * (c0.x + c1.x + bb1.x);
  o.y = w0 * (a0.y + a1.y + bb0.y) + w1 * (c0.y + c1.y + bb1.y);
  o.z = w0 * (a0.z + a1.z + bb0.z) + w1 * (c0.z + c1.z + bb1.z);
  o.w = w0 * (a0.w + a1.w + bb0.w) + w1 * (c0.w + c1.w + bb1.w);
  *(float4*)(out + (size_t)tok * DM + c4) = o;
}

__global__ void k_wsfail(float* out, float v) { if (threadIdx.x == 0) out[0] = v; }

extern "C" void kernel_launch(void* const* d_in, const int* in_sizes, int n_in,
                              void* d_out, int out_size, void* d_ws, size_t ws_size,
                              hipStream_t stream) {
  const float* x  = (const float*)d_in[0];
  const float* Wr = (const float*)d_in[1];
  const float* br = (const float*)d_in[2];
  const float* W1 = (const float*)d_in[3];
  const float* b1 = (const float*)d_in[4];
  const float* W2 = (const float*)d_in[5];
  const float* b2 = (const float*)d_in[6];
  float* out = (float*)d_out;
  char* ws = (char*)d_ws;

  // ws layout:
  //  [0,4096)        : cnt@0 fcnt@64 Psum@128 offs@192 ntiles@256 tileE@512 tileM0@1024
  //  toklist  @4096            (128 KiB)
  //  wlist    @135168          (128 KiB)
  //  tokmap   @266240          (32 KiB)
  //  tokw     @299008          (32 KiB)
  //  xb   @1 MiB   (8 MiB)
  //  w1t  @10 MiB  (64 MiB)  -- reused as P[2][8192][1024] fp32 by ffn2 (after ffn1)
  //  w2t  @80 MiB  (64 MiB)
  //  H    @144 MiB (64 MiB)
  const size_t NEED = ((size_t)144 << 20) + (size_t)8192 * DFF * 2;
  if (ws_size < NEED) {
    hipLaunchKernelGGL(k_wsfail, dim3(1), dim3(64), 0, stream, out, (float)ws_size);
    return;
  }
  int* cnt      = (int*)(ws + 0);
  int* fcnt     = (int*)(ws + 64);
  float* Psum   = (float*)(ws + 128);
  int* offs     = (int*)(ws + 192);
  int* ntiles   = (int*)(ws + 256);
  int* tileE    = (int*)(ws + 512);
  int* tileM0   = (int*)(ws + 1024);
  int* toklist  = (int*)(ws + 4096);
  float* wlist  = (float*)(ws + 135168);
  int* tokmap   = (int*)(ws + 266240);
  float* tokw   = (float*)(ws + 299008);
  unsigned short* xb  = (unsigned short*)(ws + ((size_t)1 << 20));
  unsigned short* w1t = (unsigned short*)(ws + ((size_t)10 << 20));
  float*          Pp  = (float*)(ws + ((size_t)10 << 20));   // aliases w1t (dead after ffn1)
  unsigned short* w2t = (unsigned short*)(ws + ((size_t)80 << 20));
  unsigned short* Hb  = (unsigned short*)(ws + ((size_t)144 << 20));

  hipMemsetAsync(ws, 0, 4096, stream);   // zero counters (out fully written by combine/scan)

  hipLaunchKernelGGL(k_cvt_x, dim3(NTOK * DM / 1024), dim3(256), 0, stream, x, xb);
  hipLaunchKernelGGL(k_transpose_bf, dim3(DFF / 32, DM / 32, NE), dim3(32, 8), 0, stream, W1, w1t, DM, DFF);
  hipLaunchKernelGGL(k_transpose_bf, dim3(DM / 32, DFF / 32, NE), dim3(32, 8), 0, stream, W2, w2t, DFF, DM);
  hipLaunchKernelGGL(k_router, dim3(NTOK / 32), dim3(256), 0, stream, x, Wr, br, cnt, fcnt, Psum,
                     toklist, wlist, tokmap, tokw);
  hipLaunchKernelGGL(k_scan_aux, dim3(1), dim3(64), 0, stream, cnt, fcnt, Psum, offs, ntiles, tileE, tileM0, out + (out_size - 1));
  hipLaunchKernelGGL(k_ffn1, dim3(DFF / 128, MAXTILES), dim3(256), 0, stream,
                     xb, w1t, b1, cnt, offs, ntiles, tileE, tileM0, toklist, Hb);
  hipLaunchKernelGGL(k_ffn2, dim3(DM / 128, MAXTILES, 2), dim3(256), 0, stream,
                     Hb, w2t, cnt, offs, ntiles, tileE, tileM0, Pp);
  hipLaunchKernelGGL(k_combine, dim3(NTOK), dim3(256), 0, stream,
                     Pp, b2, offs, tokmap, tokw, out);
}

// Round 4
// 628.967 us; speedup vs baseline: 2.3895x; 1.0369x over previous
//
#include <hip/hip_runtime.h>
#include <cstdint>
#include <cstddef>

#define NTOK 4096   // B*S = 2*2048
#define DM   1024   // D_MODEL
#define DFF  4096   // D_FF
#define NE   8      // experts
#define MAXTILES 72 // >= sum_e ceil(cnt[e]/128), worst case 64+7
#define BUFS 8192   // 128*64 shorts per LDS buffer

typedef __attribute__((ext_vector_type(8))) __bf16 bf16x8;
typedef __attribute__((ext_vector_type(4))) float  f32x4;

// round-to-nearest-even fp32 -> bf16
__device__ __forceinline__ unsigned short f2bf(float f) {
  union { float f; unsigned int u; } c; c.f = f;
  unsigned int u = c.u;
  return (unsigned short)((u + 0x7fffu + ((u >> 16) & 1u)) >> 16);
}

// async global->LDS, 16B per lane (global_load_lds_dwordx4)
__device__ __forceinline__ void async16(const void* g, void* l) {
  __builtin_amdgcn_global_load_lds(
      (const __attribute__((address_space(1))) void*)(uintptr_t)g,
      (__attribute__((address_space(3))) void*)(uint32_t)(uintptr_t)l,
      16, 0, 0);
}

// exact-erf GELU via Abramowitz-Stegun 7.1.26 (|err| < 1.5e-7, ~14 VALU ops)
__device__ __forceinline__ float gelu_erf(float v) {
  float u = v * 0.70710678118f;
  float az = fabsf(u);
  float t = __builtin_amdgcn_rcpf(fmaf(0.3275911f, az, 1.f));
  float p = fmaf(1.061405429f, t, -1.453152027f);
  p = fmaf(p, t, 1.421413741f);
  p = fmaf(p, t, -0.284496736f);
  p = fmaf(p, t, 0.254829592f);
  p = p * t;
  float ex = __builtin_amdgcn_exp2f(-az * az * 1.44269504089f);
  float er = fmaf(-p, ex, 1.f);
  er = copysignf(er, u);
  return 0.5f * v * (1.f + er);
}

// ---------------- transpose + convert: src[R][C] fp32 -> dst[C][R] bf16 (per expert z) ----
// 64x64 tile, 256 threads, ushort4 (8B) stores.
__global__ __launch_bounds__(256) void k_transpose_bf(const float* __restrict__ src,
                                                      unsigned short* __restrict__ dst,
                                                      int R, int C) {
  __shared__ float tile[64][65];
  int e = blockIdx.z;
  src += (size_t)e * R * C;
  dst += (size_t)e * R * C;
  int lx = threadIdx.x & 15, ly = threadIdx.x >> 4;
  int c0 = blockIdx.x * 64, r0 = blockIdx.y * 64;
#pragma unroll
  for (int q = 0; q < 4; q++) {
    int r = q * 16 + ly;
    float4 v = *(const float4*)(src + (size_t)(r0 + r) * C + c0 + lx * 4);
    tile[r][lx * 4 + 0] = v.x; tile[r][lx * 4 + 1] = v.y;
    tile[r][lx * 4 + 2] = v.z; tile[r][lx * 4 + 3] = v.w;
  }
  __syncthreads();
#pragma unroll
  for (int q = 0; q < 4; q++) {
    int cc = q * 16 + ly;
    ushort4 o;
    o.x = f2bf(tile[lx * 4 + 0][cc]);
    o.y = f2bf(tile[lx * 4 + 1][cc]);
    o.z = f2bf(tile[lx * 4 + 2][cc]);
    o.w = f2bf(tile[lx * 4 + 3][cc]);
    *(ushort4*)(dst + (size_t)(c0 + cc) * R + r0 + lx * 4) = o;
  }
}

// ---------------- router: logits, softmax, top-2, aux stats, lists + x->bf16 ----
__global__ void k_router(const float* __restrict__ x, const float* __restrict__ Wr,
                         const float* __restrict__ br, int* __restrict__ cnt,
                         int* __restrict__ fcnt, float* __restrict__ Psum,
                         int* __restrict__ toklist, float* __restrict__ wlist,
                         int* __restrict__ tokmap, float* __restrict__ tokw,
                         unsigned short* __restrict__ xb) {
  __shared__ float sP[NE];
  __shared__ int sF[NE];
  int tid = threadIdx.x;
  if (tid < NE) { sP[tid] = 0.f; sF[tid] = 0; }
  __syncthreads();
  int tok = blockIdx.x * 32 + (tid >> 3);  // 8 lanes per token, 32 tokens/block
  int e = tid & 7;
  const float* xr = x + (size_t)tok * DM;
  float acc = 0.f;
#pragma unroll 4
  for (int i = 0; i < DM; i += 4) {
    float4 xv = *(const float4*)(xr + i);
    acc = fmaf(xv.x, Wr[(i + 0) * NE + e], acc);
    acc = fmaf(xv.y, Wr[(i + 1) * NE + e], acc);
    acc = fmaf(xv.z, Wr[(i + 2) * NE + e], acc);
    acc = fmaf(xv.w, Wr[(i + 3) * NE + e], acc);
  }
  acc += br[e];
  // fold x->bf16 conversion in (row is L1-hot; lane e converts chunks e*4 + 32j)
#pragma unroll 4
  for (int j = 0; j < 32; j++) {
    int idx = e * 4 + j * 32;
    float4 v = *(const float4*)(xr + idx);
    ushort4 o; o.x = f2bf(v.x); o.y = f2bf(v.y); o.z = f2bf(v.z); o.w = f2bf(v.w);
    *(ushort4*)(xb + (size_t)tok * DM + idx) = o;
  }
  // softmax over the 8-lane group (group stays inside one 64-lane wave)
  float m = acc;
  for (int s = 1; s < 8; s <<= 1) m = fmaxf(m, __shfl_xor(m, s));
  float p = expf(acc - m);
  float sum = p;
  for (int s = 1; s < 8; s <<= 1) sum += __shfl_xor(sum, s);
  float prob = p / sum;
  atomicAdd(&sP[e], prob);
  int lanebase = (tid & 63) & ~7;
  float pv[8];
#pragma unroll
  for (int j = 0; j < 8; j++) pv[j] = __shfl(prob, lanebase + j);
  if (e == 0) {
    // top-1 (== argmax for f-histogram); ties -> lowest index, matching jax
    int i1 = 0; float v1 = pv[0];
#pragma unroll
    for (int j = 1; j < 8; j++) if (pv[j] > v1) { v1 = pv[j]; i1 = j; }
    int i2 = -1; float v2 = -1.f;
#pragma unroll
    for (int j = 0; j < 8; j++) if (j != i1 && pv[j] > v2) { v2 = pv[j]; i2 = j; }
    float inv = 1.f / (v1 + v2);
    int s1 = atomicAdd(&cnt[i1], 1);
    toklist[i1 * NTOK + s1] = tok; wlist[i1 * NTOK + s1] = v1 * inv;
    int s2 = atomicAdd(&cnt[i2], 1);
    toklist[i2 * NTOK + s2] = tok; wlist[i2 * NTOK + s2] = v2 * inv;
    tokmap[tok * 2] = (i1 << 16) | s1;  tokw[tok * 2] = v1 * inv;
    tokmap[tok * 2 + 1] = (i2 << 16) | s2; tokw[tok * 2 + 1] = v2 * inv;
    atomicAdd(&sF[i1], 1);
  }
  __syncthreads();
  if (tid < NE) { atomicAdd(&Psum[tid], sP[tid]); atomicAdd(&fcnt[tid], sF[tid]); }
}

// ---------------- prefix-sum, aux loss, dense tile table -------------
__global__ void k_scan_aux(const int* __restrict__ cnt, const int* __restrict__ fcnt,
                           const float* __restrict__ Psum, int* __restrict__ offs,
                           int* __restrict__ ntiles, int* __restrict__ tileE,
                           int* __restrict__ tileM0, float* __restrict__ aux_out) {
  if (threadIdx.x == 0) {
    int o = 0; float a = 0.f; int t = 0;
    for (int e = 0; e < NE; e++) {
      offs[e] = o; o += cnt[e];
      a += (float)fcnt[e] * Psum[e];
      for (int m0 = 0; m0 < cnt[e]; m0 += 128) { tileE[t] = e; tileM0[t] = m0; t++; }
    }
    *ntiles = t;
    aux_out[0] = 8.f * a / (4096.f * 4096.f);
  }
}

// ---------------- FFN pass 1: H = GELU(Xg @ W1 + b1), bf16 out -------------
// Software-pipelined: double-buffered LDS, prefetch tile k+1 during compute of tile k.
__global__ __launch_bounds__(256) void k_ffn1(
    const unsigned short* __restrict__ xb, const unsigned short* __restrict__ w1t,
    const float* __restrict__ b1, const int* __restrict__ cnt,
    const int* __restrict__ offs, const int* __restrict__ ntiles,
    const int* __restrict__ tileE, const int* __restrict__ tileM0,
    const int* __restrict__ toklist, unsigned short* __restrict__ H) {
  int t = blockIdx.y;
  if (t >= *ntiles) return;
  int e = tileE[t], m0 = tileM0[t];
  int cn = cnt[e];
  int n0 = blockIdx.x * 128;
  __shared__ __align__(16) unsigned short At[2 * BUFS];
  __shared__ __align__(16) unsigned short Bt[2 * BUFS];
  int tid = threadIdx.x;
  int chunk = tid & 7, rsub = tid >> 3;
  int cg = (chunk ^ (rsub & 7)) * 8;      // swizzled source chunk (shorts)
  const unsigned short* gA[4]; const unsigned short* gB[4];
  unsigned short* lA[4]; unsigned short* lB[4];
#pragma unroll
  for (int q = 0; q < 4; q++) {
    int row = q * 32 + rsub;
    int tr = m0 + row; if (tr >= cn) tr = cn - 1;   // clamp: garbage rows masked at store
    int tok = toklist[e * NTOK + tr];
    gA[q] = xb + (size_t)tok * DM + cg;
    gB[q] = w1t + ((size_t)e * DFF + n0 + row) * DM + cg;
    lA[q] = At + row * 64 + chunk * 8;   // wave-uniform base + lane*16B
    lB[q] = Bt + row * 64 + chunk * 8;
  }
  int wid = tid >> 6, lane = tid & 63;
  int mW = (wid >> 1) * 64, nW = (wid & 1) * 64;
  int lr = lane & 15, quad = lane >> 4;
  int sw = lane & 7;                      // == lr & 7
  f32x4 acc[4][4];
#pragma unroll
  for (int i = 0; i < 4; i++)
#pragma unroll
    for (int j = 0; j < 4; j++) acc[i][j] = (f32x4)(0.f);
  // prologue: stage tile 0 -> buffer 0
#pragma unroll
  for (int q = 0; q < 4; q++) async16(gA[q], lA[q]);
#pragma unroll
  for (int q = 0; q < 4; q++) async16(gB[q], lB[q]);
  const int NK = DM / 64;   // 16
  for (int k0 = 0; k0 < NK; k0++) {
    __syncthreads();        // waits tile k0 staging (issued one compute-phase ago); releases buf (k0+1)&1
    if (k0 + 1 < NK) {
      int koff = (k0 + 1) * 64;
      int nb = ((k0 + 1) & 1) * BUFS;
#pragma unroll
      for (int q = 0; q < 4; q++) async16(gA[q] + koff, lA[q] + nb);
#pragma unroll
      for (int q = 0; q < 4; q++) async16(gB[q] + koff, lB[q] + nb);
    }
    const unsigned short* Ab = At + (k0 & 1) * BUFS;
    const unsigned short* Bb = Bt + (k0 & 1) * BUFS;
#pragma unroll
    for (int kk8 = 0; kk8 < 8; kk8 += 4) {   // logical chunk base: 0 or 4
      int cs = ((kk8 + quad) ^ sw) * 8;      // swizzled chunk offset (shorts)
      bf16x8 a[4], b[4];
#pragma unroll
      for (int i = 0; i < 4; i++) a[i] = *(const bf16x8*)(Ab + (mW + i * 16 + lr) * 64 + cs);
#pragma unroll
      for (int j = 0; j < 4; j++) b[j] = *(const bf16x8*)(Bb + (nW + j * 16 + lr) * 64 + cs);
#pragma unroll
      for (int i = 0; i < 4; i++)
#pragma unroll
        for (int j = 0; j < 4; j++)
          acc[i][j] = __builtin_amdgcn_mfma_f32_16x16x32_bf16(a[i], b[j], acc[i][j], 0, 0, 0);
    }
  }
  int off = offs[e];
#pragma unroll
  for (int i = 0; i < 4; i++) {
#pragma unroll
    for (int r = 0; r < 4; r++) {
      int gr = m0 + mW + i * 16 + quad * 4 + r;   // C/D: row = quad*4+reg
      if (gr < cn) {
        size_t base = (size_t)(off + gr) * DFF + n0;
#pragma unroll
        for (int j = 0; j < 4; j++) {
          int col = nW + j * 16 + lr;             // C/D: col = lane&15
          float v = acc[i][j][r] + b1[(size_t)e * DFF + n0 + col];
          H[base + col] = f2bf(gelu_erf(v));
        }
      }
    }
  }
}

// ---------------- FFN pass 2: P[kz] = Hg @ W2 partials, split-K=2, pipelined ----
__global__ __launch_bounds__(256) void k_ffn2(
    const unsigned short* __restrict__ H, const unsigned short* __restrict__ w2t,
    const int* __restrict__ cnt, const int* __restrict__ offs,
    const int* __restrict__ ntiles, const int* __restrict__ tileE,
    const int* __restrict__ tileM0, float* __restrict__ P) {
  int t = blockIdx.y;
  if (t >= *ntiles) return;
  int e = tileE[t], m0 = tileM0[t];
  int cn = cnt[e];
  int n0 = blockIdx.x * 128;
  int kz = blockIdx.z;                    // split-K half: [kz*2048, kz*2048+2048)
  int off = offs[e];
  __shared__ __align__(16) unsigned short At[2 * BUFS];
  __shared__ __align__(16) unsigned short Bt[2 * BUFS];
  int tid = threadIdx.x;
  int chunk = tid & 7, rsub = tid >> 3;
  int cg = (chunk ^ (rsub & 7)) * 8;
  const unsigned short* gA[4]; const unsigned short* gB[4];
  unsigned short* lA[4]; unsigned short* lB[4];
  int kbeg = kz * (DFF / 2);
#pragma unroll
  for (int q = 0; q < 4; q++) {
    int row = q * 32 + rsub;
    int hr = m0 + row; if (hr >= cn) hr = cn - 1;
    gA[q] = H + (size_t)(off + hr) * DFF + kbeg + cg;
    gB[q] = w2t + ((size_t)e * DM + n0 + row) * DFF + kbeg + cg;
    lA[q] = At + row * 64 + chunk * 8;
    lB[q] = Bt + row * 64 + chunk * 8;
  }
  int wid = tid >> 6, lane = tid & 63;
  int mW = (wid >> 1) * 64, nW = (wid & 1) * 64;
  int lr = lane & 15, quad = lane >> 4;
  int sw = lane & 7;
  f32x4 acc[4][4];
#pragma unroll
  for (int i = 0; i < 4; i++)
#pragma unroll
    for (int j = 0; j < 4; j++) acc[i][j] = (f32x4)(0.f);
#pragma unroll
  for (int q = 0; q < 4; q++) async16(gA[q], lA[q]);
#pragma unroll
  for (int q = 0; q < 4; q++) async16(gB[q], lB[q]);
  const int NK = (DFF / 2) / 64;   // 32
  for (int k0 = 0; k0 < NK; k0++) {
    __syncthreads();
    if (k0 + 1 < NK) {
      int koff = (k0 + 1) * 64;
      int nb = ((k0 + 1) & 1) * BUFS;
#pragma unroll
      for (int q = 0; q < 4; q++) async16(gA[q] + koff, lA[q] + nb);
#pragma unroll
      for (int q = 0; q < 4; q++) async16(gB[q] + koff, lB[q] + nb);
    }
    const unsigned short* Ab = At + (k0 & 1) * BUFS;
    const unsigned short* Bb = Bt + (k0 & 1) * BUFS;
#pragma unroll
    for (int kk8 = 0; kk8 < 8; kk8 += 4) {
      int cs = ((kk8 + quad) ^ sw) * 8;
      bf16x8 a[4], b[4];
#pragma unroll
      for (int i = 0; i < 4; i++) a[i] = *(const bf16x8*)(Ab + (mW + i * 16 + lr) * 64 + cs);
#pragma unroll
      for (int j = 0; j < 4; j++) b[j] = *(const bf16x8*)(Bb + (nW + j * 16 + lr) * 64 + cs);
#pragma unroll
      for (int i = 0; i < 4; i++)
#pragma unroll
        for (int j = 0; j < 4; j++)
          acc[i][j] = __builtin_amdgcn_mfma_f32_16x16x32_bf16(a[i], b[j], acc[i][j], 0, 0, 0);
    }
  }
  float* Pk = P + (size_t)kz * 8192 * DM;
#pragma unroll
  for (int i = 0; i < 4; i++) {
#pragma unroll
    for (int r = 0; r < 4; r++) {
      int gr = m0 + mW + i * 16 + quad * 4 + r;
      if (gr < cn) {
        size_t base = (size_t)(off + gr) * DM + n0;
#pragma unroll
        for (int j = 0; j < 4; j++) {
          int col = nW + j * 16 + lr;
          Pk[base + col] = acc[i][j][r];   // plain store: unique row per (token,expert)
        }
      }
    }
  }
}

// ---------------- combine: out[tok] = sum_s w_s * (P0[r_s] + P1[r_s] + b2[e_s]) ----------
__global__ __launch_bounds__(256) void k_combine(
    const float* __restrict__ P, const float* __restrict__ b2,
    const int* __restrict__ offs, const int* __restrict__ tokmap,
    const float* __restrict__ tokw, float* __restrict__ out) {
  int tok = blockIdx.x;
  int c4 = threadIdx.x * 4;
  int enc0 = tokmap[tok * 2], enc1 = tokmap[tok * 2 + 1];
  float w0 = tokw[tok * 2], w1 = tokw[tok * 2 + 1];
  int e0 = enc0 >> 16, p0 = enc0 & 0xffff;
  int e1 = enc1 >> 16, p1 = enc1 & 0xffff;
  size_t r0 = (size_t)(offs[e0] + p0) * DM;
  size_t r1 = (size_t)(offs[e1] + p1) * DM;
  const size_t KZ = (size_t)8192 * DM;
  float4 a0 = *(const float4*)(P + r0 + c4);
  float4 a1 = *(const float4*)(P + KZ + r0 + c4);
  float4 c0 = *(const float4*)(P + r1 + c4);
  float4 c1 = *(const float4*)(P + KZ + r1 + c4);
  float4 bb0 = *(const float4*)(b2 + (size_t)e0 * DM + c4);
  float4 bb1 = *(const float4*)(b2 + (size_t)e1 * DM + c4);
  float4 o;
  o.x = w0 * (a0.x + a1.x + bb0.x) + w1 * (c0.x + c1.x + bb1.x);
  o.y = w0 * (a0.y + a1.y + bb0.y) + w1 * (c0.y + c1.y + bb1.y);
  o.z = w0 * (a0.z + a1.z + bb0.z) + w1 * (c0.z + c1.z + bb1.z);
  o.w = w0 * (a0.w + a1.w + bb0.w) + w1 * (c0.w + c1.w + bb1.w);
  *(float4*)(out + (size_t)tok * DM + c4) = o;
}

__global__ void k_wsfail(float* out, float v) { if (threadIdx.x == 0) out[0] = v; }

extern "C" void kernel_launch(void* const* d_in, const int* in_sizes, int n_in,
                              void* d_out, int out_size, void* d_ws, size_t ws_size,
                              hipStream_t stream) {
  const float* x  = (const float*)d_in[0];
  const float* Wr = (const float*)d_in[1];
  const float* br = (const float*)d_in[2];
  const float* W1 = (const float*)d_in[3];
  const float* b1 = (const float*)d_in[4];
  const float* W2 = (const float*)d_in[5];
  const float* b2 = (const float*)d_in[6];
  float* out = (float*)d_out;
  char* ws = (char*)d_ws;

  // ws layout:
  //  [0,4096)        : cnt@0 fcnt@64 Psum@128 offs@192 ntiles@256 tileE@512 tileM0@1024
  //  toklist  @4096            (128 KiB)
  //  wlist    @135168          (128 KiB)
  //  tokmap   @266240          (32 KiB)
  //  tokw     @299008          (32 KiB)
  //  xb   @1 MiB   (8 MiB)
  //  w1t  @10 MiB  (64 MiB)  -- reused as P[2][8192][1024] fp32 by ffn2 (after ffn1)
  //  w2t  @80 MiB  (64 MiB)
  //  H    @144 MiB (64 MiB)
  const size_t NEED = ((size_t)144 << 20) + (size_t)8192 * DFF * 2;
  if (ws_size < NEED) {
    hipLaunchKernelGGL(k_wsfail, dim3(1), dim3(64), 0, stream, out, (float)ws_size);
    return;
  }
  int* cnt      = (int*)(ws + 0);
  int* fcnt     = (int*)(ws + 64);
  float* Psum   = (float*)(ws + 128);
  int* offs     = (int*)(ws + 192);
  int* ntiles   = (int*)(ws + 256);
  int* tileE    = (int*)(ws + 512);
  int* tileM0   = (int*)(ws + 1024);
  int* toklist  = (int*)(ws + 4096);
  float* wlist  = (float*)(ws + 135168);
  int* tokmap   = (int*)(ws + 266240);
  float* tokw   = (float*)(ws + 299008);
  unsigned short* xb  = (unsigned short*)(ws + ((size_t)1 << 20));
  unsigned short* w1t = (unsigned short*)(ws + ((size_t)10 << 20));
  float*          Pp  = (float*)(ws + ((size_t)10 << 20));   // aliases w1t (dead after ffn1)
  unsigned short* w2t = (unsigned short*)(ws + ((size_t)80 << 20));
  unsigned short* Hb  = (unsigned short*)(ws + ((size_t)144 << 20));

  hipMemsetAsync(ws, 0, 4096, stream);   // zero counters

  hipLaunchKernelGGL(k_transpose_bf, dim3(DFF / 64, DM / 64, NE), dim3(256), 0, stream, W1, w1t, DM, DFF);
  hipLaunchKernelGGL(k_transpose_bf, dim3(DM / 64, DFF / 64, NE), dim3(256), 0, stream, W2, w2t, DFF, DM);
  hipLaunchKernelGGL(k_router, dim3(NTOK / 32), dim3(256), 0, stream, x, Wr, br, cnt, fcnt, Psum,
                     toklist, wlist, tokmap, tokw, xb);
  hipLaunchKernelGGL(k_scan_aux, dim3(1), dim3(64), 0, stream, cnt, fcnt, Psum, offs, ntiles, tileE, tileM0, out + (out_size - 1));
  hipLaunchKernelGGL(k_ffn1, dim3(DFF / 128, MAXTILES), dim3(256), 0, stream,
                     xb, w1t, b1, cnt, offs, ntiles, tileE, tileM0, toklist, Hb);
  hipLaunchKernelGGL(k_ffn2, dim3(DM / 128, MAXTILES, 2), dim3(256), 0, stream,
                     Hb, w2t, cnt, offs, ntiles, tileE, tileM0, Pp);
  hipLaunchKernelGGL(k_combine, dim3(NTOK), dim3(256), 0, stream,
                     Pp, b2, offs, tokmap, tokw, out);
}